// Round 1
// baseline (180.815 us; speedup 1.0000x reference)
//
#include <hip/hip_runtime.h>
#include <math.h>

// GCN link predictor, sparse-cone evaluation.
// Only h2[p0], h2[p1] matter. Passes:
//  K0  memset ctrl/deg/bitmap
//  KA  deg[dst]++ for all edges; collect edges with dst in {p0,p1} -> e1 list
//  KC  build F1 = {p0,p1} U src(e1), dedup via bitmap, pos1[] mapping
//  KD  scan edges; collect edges with dst in F1 -> e2 list
//  KE1 agg1[i] = dinv[u]^2 * x[u]          (self loop), u = F1[i]
//  KE2 agg1[pos1[u]] += dinv[w]dinv[u] x[w] for (w,u) in e2   (float atomics)
//  KF  h1[i] = relu(agg1[i] @ W1 + b1)
//  KG1 agg2[t] = dinv[p_t]^2 * h1[pos1[p_t]]
//  KG2 agg2[t] += dinv[s]dinv[p_t] h1[pos1[s]] for (s,p_t) in e1
//  KH  h2[t] = relu(agg2[t] @ W2 + b2); out = sigmoid(concat(h2) . fcW + fcb)

#define CH 64
#define E1CAP 4096
#define F1CAP (E1CAP + 2)
#define E2CAP 131072

__global__ void k_deg_e1(const int* __restrict__ src, const int* __restrict__ dst,
                         int E, const int* __restrict__ np_,
                         int* __restrict__ deg, int* __restrict__ ctrl,
                         int* __restrict__ e1s, int* __restrict__ e1d) {
    const int p0 = np_[0], p1 = np_[1];
    const int gid = blockIdx.x * blockDim.x + threadIdx.x;
    const int stride = gridDim.x * blockDim.x;
    const int nvec = ((E & 3) == 0) ? (E >> 2) : 0;
    const int4* dst4 = (const int4*)dst;
    for (int i = gid; i < nvec; i += stride) {
        int4 d4 = dst4[i];
        int ds[4] = {d4.x, d4.y, d4.z, d4.w};
#pragma unroll
        for (int k = 0; k < 4; k++) {
            int d = ds[k];
            atomicAdd(&deg[d], 1);
            if (d == p0 || d == p1) {
                int e = i * 4 + k;
                int s = src[e];
                int idx = atomicAdd(&ctrl[0], 1);
                if (idx < E1CAP) { e1s[idx] = s; e1d[idx] = d; }
            }
        }
    }
    for (int e = nvec * 4 + gid; e < E; e += stride) {
        int d = dst[e];
        atomicAdd(&deg[d], 1);
        if (d == p0 || d == p1) {
            int s = src[e];
            int idx = atomicAdd(&ctrl[0], 1);
            if (idx < E1CAP) { e1s[idx] = s; e1d[idx] = d; }
        }
    }
}

__global__ void k_build_f1(const int* __restrict__ np_, const int* __restrict__ e1s,
                           int* __restrict__ ctrl, unsigned* __restrict__ bm,
                           int* __restrict__ pos1, int* __restrict__ F1) {
    int cnt1 = min(ctrl[0], E1CAP);
    int gid = blockIdx.x * blockDim.x + threadIdx.x;
    int total = cnt1 + 2;
    if (gid >= total) return;
    int u = (gid < cnt1) ? e1s[gid] : np_[gid - cnt1];
    unsigned bit = 1u << (u & 31);
    unsigned old = atomicOr(&bm[u >> 5], bit);
    if (!(old & bit)) {
        int i = atomicAdd(&ctrl[2], 1);
        F1[i] = u;
        pos1[u] = i;
    }
}

__global__ void k_collect_e2(const int* __restrict__ src, const int* __restrict__ dst,
                             int E, const unsigned* __restrict__ bm,
                             int* __restrict__ ctrl, int* __restrict__ e2s,
                             int* __restrict__ e2d) {
    const int gid = blockIdx.x * blockDim.x + threadIdx.x;
    const int stride = gridDim.x * blockDim.x;
    const int nvec = ((E & 3) == 0) ? (E >> 2) : 0;
    const int4* dst4 = (const int4*)dst;
    for (int i = gid; i < nvec; i += stride) {
        int4 d4 = dst4[i];
        int ds[4] = {d4.x, d4.y, d4.z, d4.w};
#pragma unroll
        for (int k = 0; k < 4; k++) {
            int d = ds[k];
            if ((bm[d >> 5] >> (d & 31)) & 1u) {
                int e = i * 4 + k;
                int s = src[e];
                int idx = atomicAdd(&ctrl[1], 1);
                if (idx < E2CAP) { e2s[idx] = s; e2d[idx] = d; }
            }
        }
    }
    for (int e = nvec * 4 + gid; e < E; e += stride) {
        int d = dst[e];
        if ((bm[d >> 5] >> (d & 31)) & 1u) {
            int s = src[e];
            int idx = atomicAdd(&ctrl[1], 1);
            if (idx < E2CAP) { e2s[idx] = s; e2d[idx] = d; }
        }
    }
}

__global__ void k_agg1_init(const float* __restrict__ x, const int* __restrict__ deg,
                            const int* __restrict__ F1, const int* __restrict__ ctrl,
                            float* __restrict__ agg1) {
    int nf1 = min(ctrl[2], F1CAP);
    int j = threadIdx.x;
    for (int i = blockIdx.x; i < nf1; i += gridDim.x) {
        int u = F1[i];
        float di = rsqrtf((float)(deg[u] + 1));
        agg1[i * CH + j] = di * di * x[(size_t)u * CH + j];
    }
}

__global__ void k_agg1_edges(const float* __restrict__ x, const int* __restrict__ deg,
                             const int* __restrict__ pos1, const int* __restrict__ ctrl,
                             const int* __restrict__ e2s, const int* __restrict__ e2d,
                             float* __restrict__ agg1) {
    int cnt = min(ctrl[1], E2CAP);
    long total = (long)cnt * CH;
    long gid = blockIdx.x * blockDim.x + threadIdx.x;
    long stride = (long)gridDim.x * blockDim.x;
    for (long idx = gid; idx < total; idx += stride) {
        int e = (int)(idx >> 6);
        int c = (int)(idx & 63);
        int w = e2s[e], u = e2d[e];
        float nrm = rsqrtf((float)(deg[w] + 1)) * rsqrtf((float)(deg[u] + 1));
        atomicAdd(&agg1[pos1[u] * CH + c], nrm * x[(size_t)w * CH + c]);
    }
}

__global__ void k_h1(const float* __restrict__ agg1, const float* __restrict__ W1,
                     const float* __restrict__ b1, const int* __restrict__ ctrl,
                     float* __restrict__ h1) {
    __shared__ float a[CH];
    int nf1 = min(ctrl[2], F1CAP);
    int j = threadIdx.x;
    for (int i = blockIdx.x; i < nf1; i += gridDim.x) {
        __syncthreads();
        a[j] = agg1[i * CH + j];
        __syncthreads();
        float sum = b1[j];
#pragma unroll
        for (int k = 0; k < CH; k++) sum += a[k] * W1[k * CH + j];
        h1[i * CH + j] = fmaxf(sum, 0.f);
    }
}

__global__ void k_agg2_init(const float* __restrict__ h1, const int* __restrict__ deg,
                            const int* __restrict__ pos1, const int* __restrict__ np_,
                            float* __restrict__ agg2) {
    int t = threadIdx.x >> 6, c = threadIdx.x & 63;
    int p = np_[t];
    float di = rsqrtf((float)(deg[p] + 1));
    agg2[t * CH + c] = di * di * h1[pos1[p] * CH + c];
}

__global__ void k_agg2_edges(const float* __restrict__ h1, const int* __restrict__ deg,
                             const int* __restrict__ pos1, const int* __restrict__ np_,
                             const int* __restrict__ ctrl, const int* __restrict__ e1s,
                             const int* __restrict__ e1d, float* __restrict__ agg2) {
    int p0 = np_[0], p1 = np_[1];
    int cnt = min(ctrl[0], E1CAP);
    int total = cnt * 128;
    int gid = blockIdx.x * blockDim.x + threadIdx.x;
    int stride = gridDim.x * blockDim.x;
    for (int idx = gid; idx < total; idx += stride) {
        int e = idx >> 7;
        int r = idx & 127;
        int t = r >> 6, c = r & 63;
        int pt = t ? p1 : p0;
        int d = e1d[e];
        if (d == pt) {
            int s = e1s[e];
            float nrm = rsqrtf((float)(deg[s] + 1)) * rsqrtf((float)(deg[d] + 1));
            atomicAdd(&agg2[t * CH + c], nrm * h1[pos1[s] * CH + c]);
        }
    }
}

__global__ void k_final(const float* __restrict__ agg2, const float* __restrict__ W2,
                        const float* __restrict__ b2, const float* __restrict__ fcW,
                        const float* __restrict__ fcb, float* __restrict__ out) {
    __shared__ float a[2 * CH];
    __shared__ float partial[2];
    int tid = threadIdx.x;
    a[tid] = agg2[tid];
    __syncthreads();
    int t = tid >> 6, j = tid & 63;
    float sum = b2[j];
#pragma unroll
    for (int k = 0; k < CH; k++) sum += a[t * CH + k] * W2[k * CH + j];
    float v = fmaxf(sum, 0.f);
    float p = v * fcW[tid];
    for (int off = 32; off > 0; off >>= 1) p += __shfl_down(p, off);
    if (j == 0) partial[t] = p;
    __syncthreads();
    if (tid == 0) {
        float z = partial[0] + partial[1] + fcb[0];
        out[0] = 1.f / (1.f + expf(-z));
    }
}

extern "C" void kernel_launch(void* const* d_in, const int* in_sizes, int n_in,
                              void* d_out, int out_size, void* d_ws, size_t ws_size,
                              hipStream_t stream) {
    const float* x   = (const float*)d_in[0];
    const int*   ei  = (const int*)d_in[1];
    const int*   np_ = (const int*)d_in[2];
    const float* W1  = (const float*)d_in[3];
    const float* b1  = (const float*)d_in[4];
    const float* W2  = (const float*)d_in[5];
    const float* b2  = (const float*)d_in[6];
    const float* fcW = (const float*)d_in[7];
    const float* fcb = (const float*)d_in[8];

    const int N = in_sizes[0] / CH;
    const int E = in_sizes[1] / 2;
    const int* src = ei;
    const int* dst = ei + E;

    // workspace layout
    char* w = (char*)d_ws;
    size_t off = 0;
    auto alloc = [&](size_t bytes) {
        size_t o = off;
        off = (off + bytes + 15) & ~((size_t)15);
        return o;
    };
    size_t o_ctrl = alloc(16);                  // [0]=cnt_e1 [1]=cnt_e2 [2]=nf1
    size_t o_deg  = alloc((size_t)N * 4);
    int bmN = (N + 31) / 32;
    size_t o_bm   = alloc((size_t)bmN * 4);
    size_t zero_end = off;                      // zeroed region ends here
    size_t o_pos  = alloc((size_t)N * 4);
    size_t o_e1s  = alloc((size_t)E1CAP * 4);
    size_t o_e1d  = alloc((size_t)E1CAP * 4);
    size_t o_F1   = alloc((size_t)F1CAP * 4);
    size_t o_e2s  = alloc((size_t)E2CAP * 4);
    size_t o_e2d  = alloc((size_t)E2CAP * 4);
    size_t o_agg1 = alloc((size_t)F1CAP * CH * 4);
    size_t o_h1   = alloc((size_t)F1CAP * CH * 4);
    size_t o_agg2 = alloc((size_t)2 * CH * 4);
    (void)o_agg2; (void)ws_size;

    int*      ctrl = (int*)(w + o_ctrl);
    int*      deg  = (int*)(w + o_deg);
    unsigned* bm   = (unsigned*)(w + o_bm);
    int*      pos1 = (int*)(w + o_pos);
    int*      e1s  = (int*)(w + o_e1s);
    int*      e1d  = (int*)(w + o_e1d);
    int*      F1   = (int*)(w + o_F1);
    int*      e2s  = (int*)(w + o_e2s);
    int*      e2d  = (int*)(w + o_e2d);
    float*    agg1 = (float*)(w + o_agg1);
    float*    h1   = (float*)(w + o_h1);
    float*    agg2 = (float*)(w + o_agg2);

    hipMemsetAsync(d_ws, 0, zero_end, stream);

    int scanBlocks = (E / 4 + 255) / 256;
    if (scanBlocks < 1) scanBlocks = 1;
    if (scanBlocks > 8192) scanBlocks = 8192;

    k_deg_e1<<<scanBlocks, 256, 0, stream>>>(src, dst, E, np_, deg, ctrl, e1s, e1d);
    k_build_f1<<<(E1CAP + 2 + 255) / 256, 256, 0, stream>>>(np_, e1s, ctrl, bm, pos1, F1);
    k_collect_e2<<<scanBlocks, 256, 0, stream>>>(src, dst, E, bm, ctrl, e2s, e2d);
    k_agg1_init<<<64, CH, 0, stream>>>(x, deg, F1, ctrl, agg1);
    k_agg1_edges<<<128, 256, 0, stream>>>(x, deg, pos1, ctrl, e2s, e2d, agg1);
    k_h1<<<64, CH, 0, stream>>>(agg1, W1, b1, ctrl, h1);
    k_agg2_init<<<1, 128, 0, stream>>>(h1, deg, pos1, np_, agg2);
    k_agg2_edges<<<8, 256, 0, stream>>>(h1, deg, pos1, np_, ctrl, e1s, e1d, agg2);
    k_final<<<1, 128, 0, stream>>>(agg2, W2, b2, fcW, fcb, (float*)d_out);
}

// Round 2
// 125.209 us; speedup vs baseline: 1.4441x; 1.4441x over previous
//
#include <hip/hip_runtime.h>
#include <math.h>

// GCN link predictor, sparse-cone evaluation (round 2).
// Key change vs round 1: no full-degree atomic pass (1.6M device-scope
// atomics = 50 MB HBM-side traffic, 67 us). Degrees computed only for the
// ~600 nodes in the 2-hop dependence cone via a need-bitmap.
//
// Passes:
//  M   memset ctrl/deg/bitmaps/agg1e
//  K1  scan dst: collect e1 = edges with dst in {p0,p1}          (no atomics)
//  K2  build F1 = {p0,p1} U src(e1); bmF1 + need bits + pos1
//  K3  scan dst: collect e2 = edges with dst in F1; need-bit src(e2)
//  K4  scan dst: deg[d]++ only if need-bit[d]   (~10k atomics)
//  K5  agg1e[pos1[u]][c] += dinv[w]dinv[u] x[w][c]  over e2 (global atomics)
//  K6  h1[i] = relu((agg1e[i] + dinv[u]^2 x[u]) @ W1 + b1),  u = F1[i]
//  K7  agg2/h2/fc/sigmoid tail (1 block)

#define CH 64
#define E1CAP 4096
#define F1CAP (E1CAP + 2)
#define E2CAP 131072

__device__ __forceinline__ float dinv_of(int degv) {
    return rsqrtf((float)(degv + 1));
}

__global__ void k_e1(const int* __restrict__ src, const int* __restrict__ dst,
                     int E, const int* __restrict__ np_,
                     int* __restrict__ ctrl,
                     int* __restrict__ e1s, int* __restrict__ e1d) {
    const int p0 = np_[0], p1 = np_[1];
    const int gid = blockIdx.x * blockDim.x + threadIdx.x;
    const int stride = gridDim.x * blockDim.x;
    const int nvec = E >> 2;
    const int4* dst4 = (const int4*)dst;
    for (int i = gid; i < nvec; i += stride) {
        int4 d4 = dst4[i];
        int ds[4] = {d4.x, d4.y, d4.z, d4.w};
#pragma unroll
        for (int k = 0; k < 4; k++) {
            int d = ds[k];
            if (d == p0 || d == p1) {
                int e = i * 4 + k;
                int s = src[e];
                int idx = atomicAdd(&ctrl[0], 1);
                if (idx < E1CAP) { e1s[idx] = s; e1d[idx] = d; }
            }
        }
    }
    for (int e = (nvec << 2) + gid; e < E; e += stride) {
        int d = dst[e];
        if (d == p0 || d == p1) {
            int s = src[e];
            int idx = atomicAdd(&ctrl[0], 1);
            if (idx < E1CAP) { e1s[idx] = s; e1d[idx] = d; }
        }
    }
}

__global__ void k_build_f1(const int* __restrict__ np_, const int* __restrict__ e1s,
                           int* __restrict__ ctrl, unsigned* __restrict__ bmF1,
                           unsigned* __restrict__ bmNeed,
                           int* __restrict__ pos1, int* __restrict__ F1) {
    int cnt1 = min(ctrl[0], E1CAP);
    int gid = blockIdx.x * blockDim.x + threadIdx.x;
    int total = cnt1 + 2;
    if (gid >= total) return;
    int u = (gid < cnt1) ? e1s[gid] : np_[gid - cnt1];
    unsigned bit = 1u << (u & 31);
    unsigned old = atomicOr(&bmF1[u >> 5], bit);
    if (!(old & bit)) {
        atomicOr(&bmNeed[u >> 5], bit);
        int i = atomicAdd(&ctrl[2], 1);
        F1[i] = u;
        pos1[u] = i;
    }
}

__global__ void k_e2(const int* __restrict__ src, const int* __restrict__ dst,
                     int E, const unsigned* __restrict__ bmF1,
                     unsigned* __restrict__ bmNeed,
                     int* __restrict__ ctrl, int* __restrict__ e2s,
                     int* __restrict__ e2d) {
    const int gid = blockIdx.x * blockDim.x + threadIdx.x;
    const int stride = gridDim.x * blockDim.x;
    const int nvec = E >> 2;
    const int4* dst4 = (const int4*)dst;
    for (int i = gid; i < nvec; i += stride) {
        int4 d4 = dst4[i];
        int ds[4] = {d4.x, d4.y, d4.z, d4.w};
#pragma unroll
        for (int k = 0; k < 4; k++) {
            int d = ds[k];
            if ((bmF1[d >> 5] >> (d & 31)) & 1u) {
                int e = i * 4 + k;
                int s = src[e];
                atomicOr(&bmNeed[s >> 5], 1u << (s & 31));
                int idx = atomicAdd(&ctrl[1], 1);
                if (idx < E2CAP) { e2s[idx] = s; e2d[idx] = d; }
            }
        }
    }
    for (int e = (nvec << 2) + gid; e < E; e += stride) {
        int d = dst[e];
        if ((bmF1[d >> 5] >> (d & 31)) & 1u) {
            int s = src[e];
            atomicOr(&bmNeed[s >> 5], 1u << (s & 31));
            int idx = atomicAdd(&ctrl[1], 1);
            if (idx < E2CAP) { e2s[idx] = s; e2d[idx] = d; }
        }
    }
}

__global__ void k_deg(const int* __restrict__ dst, int E,
                      const unsigned* __restrict__ bmNeed,
                      int* __restrict__ deg) {
    const int gid = blockIdx.x * blockDim.x + threadIdx.x;
    const int stride = gridDim.x * blockDim.x;
    const int nvec = E >> 2;
    const int4* dst4 = (const int4*)dst;
    for (int i = gid; i < nvec; i += stride) {
        int4 d4 = dst4[i];
        int ds[4] = {d4.x, d4.y, d4.z, d4.w};
#pragma unroll
        for (int k = 0; k < 4; k++) {
            int d = ds[k];
            if ((bmNeed[d >> 5] >> (d & 31)) & 1u) atomicAdd(&deg[d], 1);
        }
    }
    for (int e = (nvec << 2) + gid; e < E; e += stride) {
        int d = dst[e];
        if ((bmNeed[d >> 5] >> (d & 31)) & 1u) atomicAdd(&deg[d], 1);
    }
}

__global__ void k_agg1_edges(const float* __restrict__ x, const int* __restrict__ deg,
                             const int* __restrict__ pos1, const int* __restrict__ ctrl,
                             const int* __restrict__ e2s, const int* __restrict__ e2d,
                             float* __restrict__ agg1e) {
    int cnt = min(ctrl[1], E2CAP);
    long total = (long)cnt * CH;
    long gid = blockIdx.x * blockDim.x + threadIdx.x;
    long stride = (long)gridDim.x * blockDim.x;
    for (long idx = gid; idx < total; idx += stride) {
        int e = (int)(idx >> 6);          // all 64 lanes of a wave share e
        int c = (int)(idx & 63);
        int w = e2s[e], u = e2d[e];
        float nrm = dinv_of(deg[w]) * dinv_of(deg[u]);
        atomicAdd(&agg1e[pos1[u] * CH + c], nrm * x[(size_t)w * CH + c]);
    }
}

// 256 threads = 4 waves, one row per wave
__global__ void k_h1(const float* __restrict__ x, const float* __restrict__ agg1e,
                     const float* __restrict__ W1, const float* __restrict__ b1,
                     const int* __restrict__ deg, const int* __restrict__ F1,
                     const int* __restrict__ ctrl, float* __restrict__ h1) {
    __shared__ float a[4][CH];
    int nf1 = min(ctrl[2], F1CAP);
    int w = threadIdx.x >> 6, j = threadIdx.x & 63;
    for (int base = blockIdx.x * 4; base < nf1; base += gridDim.x * 4) {
        int i = base + w;
        __syncthreads();
        if (i < nf1) {
            int u = F1[i];
            float di = dinv_of(deg[u]);
            a[w][j] = agg1e[i * CH + j] + di * di * x[(size_t)u * CH + j];
        }
        __syncthreads();
        if (i < nf1) {
            float sum = b1[j];
#pragma unroll
            for (int k = 0; k < CH; k++) sum += a[w][k] * W1[k * CH + j];
            h1[i * CH + j] = fmaxf(sum, 0.f);
        }
    }
}

__global__ void k_tail(const float* __restrict__ h1, const int* __restrict__ deg,
                       const int* __restrict__ pos1, const int* __restrict__ np_,
                       const int* __restrict__ ctrl, const int* __restrict__ e1s,
                       const int* __restrict__ e1d,
                       const float* __restrict__ W2, const float* __restrict__ b2,
                       const float* __restrict__ fcW, const float* __restrict__ fcb,
                       float* __restrict__ out) {
    __shared__ float a[2][CH];
    __shared__ float partial[2];
    int tid = threadIdx.x;
    int t = tid >> 6, j = tid & 63;
    int p = np_[t];
    float dp = dinv_of(deg[p]);
    float acc = dp * dp * h1[pos1[p] * CH + j];
    int cnt1 = min(ctrl[0], E1CAP);
    for (int e = 0; e < cnt1; e++) {
        int d = e1d[e];
        if (d == p) {
            int s = e1s[e];
            acc += dinv_of(deg[s]) * dp * h1[pos1[s] * CH + j];
        }
    }
    a[t][j] = acc;
    __syncthreads();
    float sum = b2[j];
#pragma unroll
    for (int k = 0; k < CH; k++) sum += a[t][k] * W2[k * CH + j];
    float v = fmaxf(sum, 0.f);
    float pr = v * fcW[t * CH + j];
    for (int off = 32; off > 0; off >>= 1) pr += __shfl_down(pr, off);
    if (j == 0) partial[t] = pr;
    __syncthreads();
    if (tid == 0) {
        float z = partial[0] + partial[1] + fcb[0];
        out[0] = 1.f / (1.f + expf(-z));
    }
}

extern "C" void kernel_launch(void* const* d_in, const int* in_sizes, int n_in,
                              void* d_out, int out_size, void* d_ws, size_t ws_size,
                              hipStream_t stream) {
    const float* x   = (const float*)d_in[0];
    const int*   ei  = (const int*)d_in[1];
    const int*   np_ = (const int*)d_in[2];
    const float* W1  = (const float*)d_in[3];
    const float* b1  = (const float*)d_in[4];
    const float* W2  = (const float*)d_in[5];
    const float* b2  = (const float*)d_in[6];
    const float* fcW = (const float*)d_in[7];
    const float* fcb = (const float*)d_in[8];

    const int N = in_sizes[0] / CH;
    const int E = in_sizes[1] / 2;
    const int* src = ei;
    const int* dst = ei + E;

    char* w = (char*)d_ws;
    size_t off = 0;
    auto alloc = [&](size_t bytes) {
        size_t o = off;
        off = (off + bytes + 255) & ~((size_t)255);
        return o;
    };
    // --- zeroed region ---
    size_t o_ctrl  = alloc(64);                       // [0]=cnt_e1 [1]=cnt_e2 [2]=nf1
    size_t o_deg   = alloc((size_t)N * 4);
    int bmN = (N + 31) / 32;
    size_t o_bmF1  = alloc((size_t)bmN * 4);
    size_t o_bmNd  = alloc((size_t)bmN * 4);
    size_t o_agg1e = alloc((size_t)F1CAP * CH * 4);
    size_t zero_end = off;
    // --- uninitialized region ---
    size_t o_pos  = alloc((size_t)N * 4);
    size_t o_e1s  = alloc((size_t)E1CAP * 4);
    size_t o_e1d  = alloc((size_t)E1CAP * 4);
    size_t o_F1   = alloc((size_t)F1CAP * 4);
    size_t o_e2s  = alloc((size_t)E2CAP * 4);
    size_t o_e2d  = alloc((size_t)E2CAP * 4);
    size_t o_h1   = alloc((size_t)F1CAP * CH * 4);
    (void)ws_size;

    int*      ctrl  = (int*)(w + o_ctrl);
    int*      deg   = (int*)(w + o_deg);
    unsigned* bmF1  = (unsigned*)(w + o_bmF1);
    unsigned* bmNd  = (unsigned*)(w + o_bmNd);
    float*    agg1e = (float*)(w + o_agg1e);
    int*      pos1  = (int*)(w + o_pos);
    int*      e1s   = (int*)(w + o_e1s);
    int*      e1d   = (int*)(w + o_e1d);
    int*      F1    = (int*)(w + o_F1);
    int*      e2s   = (int*)(w + o_e2s);
    int*      e2d   = (int*)(w + o_e2d);
    float*    h1    = (float*)(w + o_h1);

    hipMemsetAsync(d_ws, 0, zero_end, stream);

    int scanBlocks = (E / 4 + 255) / 256;
    if (scanBlocks < 1) scanBlocks = 1;
    if (scanBlocks > 8192) scanBlocks = 8192;

    k_e1<<<scanBlocks, 256, 0, stream>>>(src, dst, E, np_, ctrl, e1s, e1d);
    k_build_f1<<<(F1CAP + 255) / 256, 256, 0, stream>>>(np_, e1s, ctrl, bmF1, bmNd, pos1, F1);
    k_e2<<<scanBlocks, 256, 0, stream>>>(src, dst, E, bmF1, bmNd, ctrl, e2s, e2d);
    k_deg<<<scanBlocks, 256, 0, stream>>>(dst, E, bmNd, deg);
    k_agg1_edges<<<256, 256, 0, stream>>>(x, deg, pos1, ctrl, e2s, e2d, agg1e);
    k_h1<<<160, 256, 0, stream>>>(x, agg1e, W1, b1, deg, F1, ctrl, h1);
    k_tail<<<1, 128, 0, stream>>>(h1, deg, pos1, np_, ctrl, e1s, e1d, W2, b2, fcW, fcb,
                                  (float*)d_out);
}